// Round 4
// baseline (145.313 us; speedup 1.0000x reference)
//
#include <hip/hip_runtime.h>
#include <hip/hip_bf16.h>

#define LL 2048
#define DM 512
// (1/sqrt(2048)) * log2(e): softmax exp(x) computed as exp2(x'); fold into Q pre-scale
#define SCALE2 0.031879357f

typedef unsigned short u16;
typedef __attribute__((ext_vector_type(8))) short short8;    // 8 bf16 (4 VGPRs)
typedef __attribute__((ext_vector_type(4))) short short4v;   // 4 bf16 (2 VGPRs)
typedef __attribute__((ext_vector_type(4))) float f32x4;     // MFMA C/D

// ws layout (u16 element offsets), ~27 MB of the 256 MiB ws:
//  XAQ/XAK/XAV: bf16 inputs in proj-A-frag order [2][128 r16][16 kt][64 lane][8]
//  WB : bf16 weights in B-frag order [3][8][16 kt][4 nt][64 lane][8]
//  QA/KA: bf16 Q,K projections in frag order (Q pre-scaled by SCALE2)
//  VB : bf16 V in PV-B-frag order (RAW; Sinv applied to P in attn)
//  S  : f32 Sinv [16][2048] (written by stats, one block per (bh,KT))
#define XAQ_OFF 0u
#define XAK_OFF 2097152u
#define XAV_OFF 4194304u
#define WB_OFF  6291456u
#define QA_OFF  7077888u
#define KA_OFF  9175040u
#define VB_OFF  11272192u
#define S_OFF   13369344u    // float region, 32768 floats

__device__ __forceinline__ u16 f2bf(float f) {
  union { float f; unsigned u; } v; v.f = f;
  unsigned r = v.u + 0x7fff + ((v.u >> 16) & 1);   // RNE
  return (u16)(r >> 16);
}
__device__ __forceinline__ size_t frag_idx(int bh, int t64, int w, int c, int lane) {
  return ((((size_t)(bh * 32 + t64) * 4 + w) * 2 + c) * 64 + lane) * 8;
}
__device__ __forceinline__ size_t vb_idx(int bh, int kt, int w, int et, int lane) {
  return ((((size_t)(bh * 32 + kt) * 4 + w) * 4 + et) * 64 + lane) * 4;
}

// ---------------- prep: X -> frag order via LDS transpose; W -> B-frag order ----------------
__global__ __launch_bounds__(256) void prep_kernel(
    const float* __restrict__ queries, const float* __restrict__ keys,
    const float* __restrict__ values, const float* __restrict__ WQ,
    const float* __restrict__ WK, const float* __restrict__ WV,
    u16* __restrict__ wsb) {
  int t = threadIdx.x;
  int blk = blockIdx.x;
  if (blk < 768) {
    int tens = blk >> 8;                       // 0=Q,1=K,2=V
    int grp  = blk & 255;                      // b*128 + r16
    const float* src = (tens == 0 ? queries : tens == 1 ? keys : values) +
                       (size_t)grp * 16 * 512;
    __shared__ __align__(16) u16 Xs[16][520];
#pragma unroll
    for (int rep = 0; rep < 8; ++rep) {
      int f4 = t + rep * 256;                  // 0..2047
      int row = f4 >> 7, c4 = f4 & 127;
      float4 v = *(const float4*)(src + (size_t)row * 512 + c4 * 4);
      short4v o;
      o[0] = (short)f2bf(v.x); o[1] = (short)f2bf(v.y);
      o[2] = (short)f2bf(v.z); o[3] = (short)f2bf(v.w);
      *(short4v*)&Xs[row][c4 * 4] = o;
    }
    __syncthreads();
    u16* dst = wsb + (tens == 0 ? XAQ_OFF : tens == 1 ? XAK_OFF : XAV_OFF) +
               (size_t)grp * 16 * 64 * 8;
#pragma unroll
    for (int rep = 0; rep < 4; ++rep) {
      int o = t + rep * 256;                   // kt*64 + lane
      int kt = o >> 6, lane = o & 63;
      int quad = lane >> 4, l16 = lane & 15;
      short8 v = *(const short8*)&Xs[l16][kt * 32 + quad * 8];
      *(short8*)(dst + (size_t)o * 8) = v;
    }
  } else {
    int c2 = (blk - 768) * 256 + t;            // 0..98303
    int lane = c2 & 63;
    int nt = (c2 >> 6) & 3;
    int kt = (c2 >> 8) & 15;
    int h  = (c2 >> 12) & 7;
    int z  = c2 >> 15;
    int quad = lane >> 4, l16 = lane & 15;
    const float* W = (z == 0) ? WQ : (z == 1) ? WK : WV;
    const float* src = W + ((size_t)h * DM + kt * 32 + quad * 8) * 64 + nt * 16 + l16;
    short8 o;
#pragma unroll
    for (int j = 0; j < 8; ++j) o[j] = (short)f2bf(src[(size_t)j * 64]);
    *(short8*)(wsb + WB_OFF + (size_t)c2 * 8) = o;
  }
}

// ---------------- proj: barrier-free MFMA GEMM; coalesced frag-order epilogue via LDS ----------------
__global__ __launch_bounds__(256) void proj_kernel(u16* __restrict__ wsb) {
  int t = threadIdx.x;
  int lane = t & 63, w = t >> 6, quad = lane >> 4, l16 = lane & 15;
  int z = blockIdx.z, bh = blockIdx.y, b = bh >> 3, h = bh & 7;
  int QT = blockIdx.x;

  const u16* Bw = wsb + WB_OFF + ((size_t)(z * 8 + h) * 16) * 4 * 64 * 8;
  const u16* Ab = wsb + (z == 0 ? XAQ_OFF : z == 1 ? XAK_OFF : XAV_OFF) +
      (((size_t)b * 128 + QT * 4 + w) * 16) * 64 * 8;

  f32x4 acc[4];
#pragma unroll
  for (int nt = 0; nt < 4; ++nt) acc[nt] = (f32x4){0.f, 0.f, 0.f, 0.f};

#pragma unroll 4
  for (int kt = 0; kt < 16; ++kt) {
    short8 a = *(const short8*)(Ab + ((size_t)kt * 64 + lane) * 8);
#pragma unroll
    for (int nt = 0; nt < 4; ++nt) {
      short8 bb = *(const short8*)(Bw + (((size_t)kt * 4 + nt) * 64 + lane) * 8);
      acc[nt] = __builtin_amdgcn_mfma_f32_16x16x32_bf16(a, bb, acc[nt], 0, 0, 0);
    }
  }

  __shared__ float Cs[64][68];
  float sc = (z == 0) ? SCALE2 : 1.0f;         // exp2-fold: SCALE * log2(e)
#pragma unroll
  for (int nt = 0; nt < 4; ++nt)
#pragma unroll
    for (int r = 0; r < 4; ++r)
      Cs[w * 16 + quad * 4 + r][nt * 16 + l16] = acc[nt][r] * sc;
  __syncthreads();

  if (z < 2) {
    u16* base = wsb + (z == 0 ? QA_OFF : KA_OFF);
#pragma unroll
    for (int c = 0; c < 2; ++c) {
      const float* srcr = &Cs[w * 16 + l16][c * 32 + quad * 8];
      short8 o;
#pragma unroll
      for (int j = 0; j < 8; ++j) o[j] = (short)f2bf(srcr[j]);
      *(short8*)(base + frag_idx(bh, QT, w, c, lane)) = o;
    }
  } else {
#pragma unroll
    for (int et = 0; et < 4; ++et) {
      short4v o;
#pragma unroll
      for (int j = 0; j < 4; ++j)
        o[j] = (short)f2bf(Cs[w * 16 + quad * 4 + j][et * 16 + l16]);
      *(short4v*)(wsb + VB_OFF + vb_idx(bh, QT, w, et, lane)) = o;
    }
  }
}

// ---------------- stats: one block per (bh,KT); Sinv[k] = 1/sum_q exp2(K·Q^T) ----------------
// 512-thread blocks: 8 waves = (q-quad w4q) x (mt-half m2). Same grid (16,32) ->
// 4096 waves total = 4 waves/SIMD (was 2), per-wave serial chain halved.
__global__ __launch_bounds__(512, 4) void stats_kernel(u16* __restrict__ wsb) {
  int t = threadIdx.x;
  int lane = t & 63, wave = t >> 6, quad = lane >> 4, l16 = lane & 15;
  int w4q = wave & 3;        // q sub-quad within each qt
  int m2  = wave >> 2;       // mt-half: global mt = m2*2 + mt_local
  int bh = blockIdx.x;
  int KT = blockIdx.y;

  short8 ka[2][2];
#pragma unroll
  for (int mt = 0; mt < 2; ++mt)
#pragma unroll
    for (int c = 0; c < 2; ++c)
      ka[mt][c] = *(const short8*)(wsb + KA_OFF + frag_idx(bh, KT, m2 * 2 + mt, c, lane));

  float rs[2][4];
#pragma unroll
  for (int mt = 0; mt < 2; ++mt)
#pragma unroll
    for (int r = 0; r < 4; ++r) rs[mt][r] = 0.f;

  // 1-deep prefetch of next qt's Q fragments (wrap on last iter; values unused)
  short8 qb0 = *(const short8*)(wsb + QA_OFF + frag_idx(bh, 0, w4q, 0, lane));
  short8 qb1 = *(const short8*)(wsb + QA_OFF + frag_idx(bh, 0, w4q, 1, lane));
  for (int qt = 0; qt < 32; ++qt) {
    int qn = (qt + 1) & 31;
    short8 nq0 = *(const short8*)(wsb + QA_OFF + frag_idx(bh, qn, w4q, 0, lane));
    short8 nq1 = *(const short8*)(wsb + QA_OFF + frag_idx(bh, qn, w4q, 1, lane));
#pragma unroll
    for (int mt = 0; mt < 2; ++mt) {
      f32x4 y = (f32x4){0.f, 0.f, 0.f, 0.f};
      __builtin_amdgcn_s_setprio(1);
      y = __builtin_amdgcn_mfma_f32_16x16x32_bf16(ka[mt][0], qb0, y, 0, 0, 0);
      y = __builtin_amdgcn_mfma_f32_16x16x32_bf16(ka[mt][1], qb1, y, 0, 0, 0);
      __builtin_amdgcn_s_setprio(0);
#pragma unroll
      for (int r = 0; r < 4; ++r) rs[mt][r] += __builtin_amdgcn_exp2f(y[r]);
    }
    qb0 = nq0; qb1 = nq1;
  }
#pragma unroll
  for (int mt = 0; mt < 2; ++mt)
#pragma unroll
    for (int r = 0; r < 4; ++r) {
      rs[mt][r] += __shfl_xor(rs[mt][r], 1);
      rs[mt][r] += __shfl_xor(rs[mt][r], 2);
      rs[mt][r] += __shfl_xor(rs[mt][r], 4);
      rs[mt][r] += __shfl_xor(rs[mt][r], 8);
    }

  // Sred[q-quad][k]: m2=0 waves fill k<32, m2=1 waves fill k>=32 (disjoint)
  __shared__ float Sred[4][64];
  if (l16 == 0) {
#pragma unroll
    for (int mt = 0; mt < 2; ++mt)
#pragma unroll
      for (int r = 0; r < 4; ++r)
        Sred[w4q][(m2 * 2 + mt) * 16 + quad * 4 + r] = rs[mt][r];
  }
  __syncthreads();
  if (t < 64) {
    float s = Sred[0][t] + Sred[1][t] + Sred[2][t] + Sred[3][t];
    float* S = (float*)(wsb + S_OFF);
    S[(size_t)bh * LL + KT * 64 + t] = 1.0f / s;
  }
}

// ---------------- attn: P = exp2(y)*Sinv[k] in registers; direct out ----------------
// 512-thread blocks: 8 waves = (key-quad w4) x (nt-half n2). Same grid (16,32) ->
// 4 waves/SIMD (was 2, LDS-capped); per-wave serial chain halved; VGPR ~halved.
__global__ __launch_bounds__(512, 4) void attn_kernel(const u16* __restrict__ wsb,
                                                      float* __restrict__ out) {
  int t = threadIdx.x;
  int lane = t & 63, wave = t >> 6, quad = lane >> 4, l16 = lane & 15;
  int w4 = wave & 3;         // key sub-quad within each kt
  int n2 = wave >> 2;        // nt-half: global nt = n2*2 + j
  int bh = blockIdx.x, b = bh >> 3, h = bh & 7;
  int QT = blockIdx.y, qbase = QT * 64;
  const float* S = (const float*)(wsb + S_OFF) + (size_t)bh * LL;

  short8 qf[2][2];
#pragma unroll
  for (int j = 0; j < 2; ++j)
#pragma unroll
    for (int c = 0; c < 2; ++c)
      qf[j][c] = *(const short8*)(wsb + QA_OFF + frag_idx(bh, QT, n2 * 2 + j, c, lane));

  f32x4 oacc[2][4];
#pragma unroll
  for (int j = 0; j < 2; ++j)
#pragma unroll
    for (int et = 0; et < 4; ++et) oacc[j][et] = (f32x4){0.f, 0.f, 0.f, 0.f};

  // 1-deep prefetch of next kt's K/V fragments and Sinv (wrap on last iter)
  short8 ka0 = *(const short8*)(wsb + KA_OFF + frag_idx(bh, 0, w4, 0, lane));
  short8 ka1 = *(const short8*)(wsb + KA_OFF + frag_idx(bh, 0, w4, 1, lane));
  short4v vb[4];
#pragma unroll
  for (int et = 0; et < 4; ++et)
    vb[et] = *(const short4v*)(wsb + VB_OFF + vb_idx(bh, 0, w4, et, lane));
  float4 s4 = *(const float4*)(S + w4 * 16 + quad * 4);

  for (int kt = 0; kt < 32; ++kt) {
    int kn = (kt + 1) & 31;
    short8 nka0 = *(const short8*)(wsb + KA_OFF + frag_idx(bh, kn, w4, 0, lane));
    short8 nka1 = *(const short8*)(wsb + KA_OFF + frag_idx(bh, kn, w4, 1, lane));
    short4v nvb[4];
#pragma unroll
    for (int et = 0; et < 4; ++et)
      nvb[et] = *(const short4v*)(wsb + VB_OFF + vb_idx(bh, kn, w4, et, lane));
    float4 ns4 = *(const float4*)(S + kn * 64 + w4 * 16 + quad * 4);

#pragma unroll
    for (int j = 0; j < 2; ++j) {
      f32x4 y = (f32x4){0.f, 0.f, 0.f, 0.f};
      __builtin_amdgcn_s_setprio(1);
      y = __builtin_amdgcn_mfma_f32_16x16x32_bf16(ka0, qf[j][0], y, 0, 0, 0);
      y = __builtin_amdgcn_mfma_f32_16x16x32_bf16(ka1, qf[j][1], y, 0, 0, 0);
      __builtin_amdgcn_s_setprio(0);
      float e0 = __builtin_amdgcn_exp2f(y[0]) * s4.x;
      float e1 = __builtin_amdgcn_exp2f(y[1]) * s4.y;
      float e2 = __builtin_amdgcn_exp2f(y[2]) * s4.z;
      float e3 = __builtin_amdgcn_exp2f(y[3]) * s4.w;
      short4v pa;
      pa[0] = (short)f2bf(e0);
      pa[1] = (short)f2bf(e1);
      pa[2] = (short)f2bf(e2);
      pa[3] = (short)f2bf(e3);
      __builtin_amdgcn_s_setprio(1);
#pragma unroll
      for (int et = 0; et < 4; ++et)
        oacc[j][et] = __builtin_amdgcn_mfma_f32_16x16x16bf16_1k(pa, vb[et], oacc[j][et], 0, 0, 0);
      __builtin_amdgcn_s_setprio(0);
    }
    ka0 = nka0; ka1 = nka1;
#pragma unroll
    for (int et = 0; et < 4; ++et) vb[et] = nvb[et];
    s4 = ns4;
  }

  // red[key-quad][qrow][e]: n2=0 waves fill qrows 0-31, n2=1 fill 32-63 (disjoint)
  __shared__ float red[4][64][68];
#pragma unroll
  for (int j = 0; j < 2; ++j)
#pragma unroll
    for (int et = 0; et < 4; ++et)
#pragma unroll
      for (int r = 0; r < 4; ++r)
        red[w4][(n2 * 2 + j) * 16 + quad * 4 + r][et * 16 + l16] = oacc[j][et][r];
  __syncthreads();
  // each of the 8 waves writes 8 output rows
  float* og = out + ((size_t)b * LL + qbase + wave * 8) * 512 + h * 64;
#pragma unroll
  for (int i = 0; i < 8; ++i) {
    int row = wave * 8 + i;
    float s = red[0][row][lane] + red[1][row][lane] +
              red[2][row][lane] + red[3][row][lane];
    og[(size_t)i * 512 + lane] = s;
  }
}

extern "C" void kernel_launch(void* const* d_in, const int* in_sizes, int n_in,
                              void* d_out, int out_size, void* d_ws, size_t ws_size,
                              hipStream_t stream) {
  const float* keys    = (const float*)d_in[0];
  const float* queries = (const float*)d_in[1];
  const float* values  = (const float*)d_in[2];
  const float* WQ      = (const float*)d_in[3];
  const float* WK      = (const float*)d_in[4];
  const float* WV      = (const float*)d_in[5];
  float* out = (float*)d_out;
  u16* wsb = (u16*)d_ws;

  prep_kernel<<<dim3(1152), 256, 0, stream>>>(queries, keys, values, WQ, WK, WV, wsb);
  proj_kernel<<<dim3(32, 16, 3), 256, 0, stream>>>(wsb);
  stats_kernel<<<dim3(16, 32), 512, 0, stream>>>(wsb);
  attn_kernel<<<dim3(16, 32), 512, 0, stream>>>(wsb, out);
}

// Round 5
// 135.437 us; speedup vs baseline: 1.0729x; 1.0729x over previous
//
#include <hip/hip_runtime.h>
#include <hip/hip_bf16.h>

#define LL 2048
#define DM 512
// (1/sqrt(2048)) * log2(e): softmax exp(x) computed as exp2(x'); fold into Q pre-scale
#define SCALE2 0.031879357f

typedef unsigned short u16;
typedef __attribute__((ext_vector_type(8))) short short8;    // 8 bf16 (4 VGPRs)
typedef __attribute__((ext_vector_type(4))) short short4v;   // 4 bf16 (2 VGPRs)
typedef __attribute__((ext_vector_type(4))) float f32x4;     // MFMA C/D

// ws layout (u16 element offsets), ~27 MB of the 256 MiB ws:
//  XAQ/XAK/XAV: bf16 inputs in proj-A-frag order [2][128 r16][16 kt][64 lane][8]
//  WB : bf16 weights in B-frag order [3][8][16 kt][4 nt][64 lane][8]
//  QA/KA: bf16 Q,K projections in frag order (Q pre-scaled by SCALE2)
//  VB : bf16 V in PAIRED PV-B-frag order [16 kt2][4 w][4 et][64 lane][8]
//       (j<4 = keys of kt=2*kt2, j>=4 = keys of kt=2*kt2+1) for K=32 PV MFMA
//  S  : f32 Sinv [16][2048] (written by stats, one block per (bh,KT))
#define XAQ_OFF 0u
#define XAK_OFF 2097152u
#define XAV_OFF 4194304u
#define WB_OFF  6291456u
#define QA_OFF  7077888u
#define KA_OFF  9175040u
#define VB_OFF  11272192u
#define S_OFF   13369344u    // float region, 32768 floats

__device__ __forceinline__ u16 f2bf(float f) {
  union { float f; unsigned u; } v; v.f = f;
  unsigned r = v.u + 0x7fff + ((v.u >> 16) & 1);   // RNE
  return (u16)(r >> 16);
}
__device__ __forceinline__ size_t frag_idx(int bh, int t64, int w, int c, int lane) {
  return ((((size_t)(bh * 32 + t64) * 4 + w) * 2 + c) * 64 + lane) * 8;
}
// paired VB layout for K=32 PV: 16B word per (kt2,w,et,lane)
__device__ __forceinline__ size_t vb8_idx(int bh, int kt2, int w, int et, int lane) {
  return ((((size_t)(bh * 16 + kt2) * 4 + w) * 4 + et) * 64 + lane) * 8;
}

// ---------------- prep: X -> frag order via LDS transpose; W -> B-frag order ----------------
__global__ __launch_bounds__(256) void prep_kernel(
    const float* __restrict__ queries, const float* __restrict__ keys,
    const float* __restrict__ values, const float* __restrict__ WQ,
    const float* __restrict__ WK, const float* __restrict__ WV,
    u16* __restrict__ wsb) {
  int t = threadIdx.x;
  int blk = blockIdx.x;
  if (blk < 768) {
    int tens = blk >> 8;                       // 0=Q,1=K,2=V
    int grp  = blk & 255;                      // b*128 + r16
    const float* src = (tens == 0 ? queries : tens == 1 ? keys : values) +
                       (size_t)grp * 16 * 512;
    __shared__ __align__(16) u16 Xs[16][520];
#pragma unroll
    for (int rep = 0; rep < 8; ++rep) {
      int f4 = t + rep * 256;                  // 0..2047
      int row = f4 >> 7, c4 = f4 & 127;
      float4 v = *(const float4*)(src + (size_t)row * 512 + c4 * 4);
      short4v o;
      o[0] = (short)f2bf(v.x); o[1] = (short)f2bf(v.y);
      o[2] = (short)f2bf(v.z); o[3] = (short)f2bf(v.w);
      *(short4v*)&Xs[row][c4 * 4] = o;
    }
    __syncthreads();
    u16* dst = wsb + (tens == 0 ? XAQ_OFF : tens == 1 ? XAK_OFF : XAV_OFF) +
               (size_t)grp * 16 * 64 * 8;
#pragma unroll
    for (int rep = 0; rep < 4; ++rep) {
      int o = t + rep * 256;                   // kt*64 + lane
      int kt = o >> 6, lane = o & 63;
      int quad = lane >> 4, l16 = lane & 15;
      short8 v = *(const short8*)&Xs[l16][kt * 32 + quad * 8];
      *(short8*)(dst + (size_t)o * 8) = v;
    }
  } else {
    int c2 = (blk - 768) * 256 + t;            // 0..98303
    int lane = c2 & 63;
    int nt = (c2 >> 6) & 3;
    int kt = (c2 >> 8) & 15;
    int h  = (c2 >> 12) & 7;
    int z  = c2 >> 15;
    int quad = lane >> 4, l16 = lane & 15;
    const float* W = (z == 0) ? WQ : (z == 1) ? WK : WV;
    const float* src = W + ((size_t)h * DM + kt * 32 + quad * 8) * 64 + nt * 16 + l16;
    short8 o;
#pragma unroll
    for (int j = 0; j < 8; ++j) o[j] = (short)f2bf(src[(size_t)j * 64]);
    *(short8*)(wsb + WB_OFF + (size_t)c2 * 8) = o;
  }
}

// ---------------- proj: barrier-free MFMA GEMM; coalesced frag-order epilogue via LDS ----------------
__global__ __launch_bounds__(256) void proj_kernel(u16* __restrict__ wsb) {
  int t = threadIdx.x;
  int lane = t & 63, w = t >> 6, quad = lane >> 4, l16 = lane & 15;
  int z = blockIdx.z, bh = blockIdx.y, b = bh >> 3, h = bh & 7;
  int QT = blockIdx.x;

  const u16* Bw = wsb + WB_OFF + ((size_t)(z * 8 + h) * 16) * 4 * 64 * 8;
  const u16* Ab = wsb + (z == 0 ? XAQ_OFF : z == 1 ? XAK_OFF : XAV_OFF) +
      (((size_t)b * 128 + QT * 4 + w) * 16) * 64 * 8;

  f32x4 acc[4];
#pragma unroll
  for (int nt = 0; nt < 4; ++nt) acc[nt] = (f32x4){0.f, 0.f, 0.f, 0.f};

#pragma unroll 4
  for (int kt = 0; kt < 16; ++kt) {
    short8 a = *(const short8*)(Ab + ((size_t)kt * 64 + lane) * 8);
#pragma unroll
    for (int nt = 0; nt < 4; ++nt) {
      short8 bb = *(const short8*)(Bw + (((size_t)kt * 4 + nt) * 64 + lane) * 8);
      acc[nt] = __builtin_amdgcn_mfma_f32_16x16x32_bf16(a, bb, acc[nt], 0, 0, 0);
    }
  }

  __shared__ float Cs[64][68];
  float sc = (z == 0) ? SCALE2 : 1.0f;         // exp2-fold: SCALE * log2(e)
#pragma unroll
  for (int nt = 0; nt < 4; ++nt)
#pragma unroll
    for (int r = 0; r < 4; ++r)
      Cs[w * 16 + quad * 4 + r][nt * 16 + l16] = acc[nt][r] * sc;
  __syncthreads();

  if (z < 2) {
    u16* base = wsb + (z == 0 ? QA_OFF : KA_OFF);
#pragma unroll
    for (int c = 0; c < 2; ++c) {
      const float* srcr = &Cs[w * 16 + l16][c * 32 + quad * 8];
      short8 o;
#pragma unroll
      for (int j = 0; j < 8; ++j) o[j] = (short)f2bf(srcr[j]);
      *(short8*)(base + frag_idx(bh, QT, w, c, lane)) = o;
    }
  } else {
    // paired PV-B layout: this block (kt = QT) writes the 8-byte half-word
    // (QT&1 ? j4-7 : j0-3) of each 16B K=32 B-fragment at kt2 = QT>>1
#pragma unroll
    for (int et = 0; et < 4; ++et) {
      short4v o;
#pragma unroll
      for (int j = 0; j < 4; ++j)
        o[j] = (short)f2bf(Cs[w * 16 + quad * 4 + j][et * 16 + l16]);
      *(short4v*)(wsb + VB_OFF + vb8_idx(bh, QT >> 1, w, et, lane) + (QT & 1) * 4) = o;
    }
  }
}

// ---------------- stats: one block per (bh,KT); Sinv[k] = 1/sum_q exp2(K·Q^T) ----------------
// grid (x=bh, y=KT): linear%8 == bh%8 -> all blocks of a bh land on one XCD,
// so the 32x QA re-read hits that XCD's L2 instead of L3/HBM.
__global__ __launch_bounds__(256) void stats_kernel(u16* __restrict__ wsb) {
  int t = threadIdx.x;
  int lane = t & 63, w = t >> 6, quad = lane >> 4, l16 = lane & 15;
  int bh = blockIdx.x;
  int KT = blockIdx.y;

  short8 ka[4][2];
#pragma unroll
  for (int mt = 0; mt < 4; ++mt)
#pragma unroll
    for (int c = 0; c < 2; ++c)
      ka[mt][c] = *(const short8*)(wsb + KA_OFF + frag_idx(bh, KT, mt, c, lane));

  float rs[4][4];
#pragma unroll
  for (int mt = 0; mt < 4; ++mt)
#pragma unroll
    for (int r = 0; r < 4; ++r) rs[mt][r] = 0.f;

  // 1-deep prefetch of next qt's Q fragments (wrap on last iter; values unused)
  short8 qb0 = *(const short8*)(wsb + QA_OFF + frag_idx(bh, 0, w, 0, lane));
  short8 qb1 = *(const short8*)(wsb + QA_OFF + frag_idx(bh, 0, w, 1, lane));
  for (int qt = 0; qt < 32; ++qt) {
    int qn = (qt + 1) & 31;
    short8 nq0 = *(const short8*)(wsb + QA_OFF + frag_idx(bh, qn, w, 0, lane));
    short8 nq1 = *(const short8*)(wsb + QA_OFF + frag_idx(bh, qn, w, 1, lane));
#pragma unroll
    for (int mt = 0; mt < 4; ++mt) {
      f32x4 y = (f32x4){0.f, 0.f, 0.f, 0.f};
      __builtin_amdgcn_s_setprio(1);
      y = __builtin_amdgcn_mfma_f32_16x16x32_bf16(ka[mt][0], qb0, y, 0, 0, 0);
      y = __builtin_amdgcn_mfma_f32_16x16x32_bf16(ka[mt][1], qb1, y, 0, 0, 0);
      __builtin_amdgcn_s_setprio(0);
#pragma unroll
      for (int r = 0; r < 4; ++r) rs[mt][r] += __builtin_amdgcn_exp2f(y[r]);
    }
    qb0 = nq0; qb1 = nq1;
  }
#pragma unroll
  for (int mt = 0; mt < 4; ++mt)
#pragma unroll
    for (int r = 0; r < 4; ++r) {
      rs[mt][r] += __shfl_xor(rs[mt][r], 1);
      rs[mt][r] += __shfl_xor(rs[mt][r], 2);
      rs[mt][r] += __shfl_xor(rs[mt][r], 4);
      rs[mt][r] += __shfl_xor(rs[mt][r], 8);
    }

  __shared__ float Sred[4][64];
  if (l16 == 0) {
#pragma unroll
    for (int mt = 0; mt < 4; ++mt)
#pragma unroll
      for (int r = 0; r < 4; ++r)
        Sred[w][mt * 16 + quad * 4 + r] = rs[mt][r];
  }
  __syncthreads();
  if (t < 64) {
    float s = Sred[0][t] + Sred[1][t] + Sred[2][t] + Sred[3][t];
    float* S = (float*)(wsb + S_OFF);
    S[(size_t)bh * LL + KT * 64 + t] = 1.0f / s;
  }
}

// ---------------- attn: P = exp2(y)*Sinv[k] in registers; K=32 PV MFMA; direct out ----------------
// grid (x=bh, y=QT) for the same XCD-L2 locality on KA/VB re-reads.
__global__ __launch_bounds__(256, 2) void attn_kernel(const u16* __restrict__ wsb,
                                                      float* __restrict__ out) {
  int t = threadIdx.x;
  int lane = t & 63, w = t >> 6, quad = lane >> 4, l16 = lane & 15;
  int bh = blockIdx.x, b = bh >> 3, h = bh & 7;
  int QT = blockIdx.y, qbase = QT * 64;
  const float* S = (const float*)(wsb + S_OFF) + (size_t)bh * LL;

  short8 qf[4][2];
#pragma unroll
  for (int nt = 0; nt < 4; ++nt)
#pragma unroll
    for (int c = 0; c < 2; ++c)
      qf[nt][c] = *(const short8*)(wsb + QA_OFF + frag_idx(bh, QT, nt, c, lane));

  f32x4 oacc[4][4];
#pragma unroll
  for (int nt = 0; nt < 4; ++nt)
#pragma unroll
    for (int et = 0; et < 4; ++et) oacc[nt][et] = (f32x4){0.f, 0.f, 0.f, 0.f};

  // 1-deep prefetch of next kt2's K(even,odd)/V-paired fragments and Sinv
  short8 kae0 = *(const short8*)(wsb + KA_OFF + frag_idx(bh, 0, w, 0, lane));
  short8 kae1 = *(const short8*)(wsb + KA_OFF + frag_idx(bh, 0, w, 1, lane));
  short8 kao0 = *(const short8*)(wsb + KA_OFF + frag_idx(bh, 1, w, 0, lane));
  short8 kao1 = *(const short8*)(wsb + KA_OFF + frag_idx(bh, 1, w, 1, lane));
  short8 vb8[4];
#pragma unroll
  for (int et = 0; et < 4; ++et)
    vb8[et] = *(const short8*)(wsb + VB_OFF + vb8_idx(bh, 0, w, et, lane));
  float4 s4e = *(const float4*)(S + 0 * 64 + w * 16 + quad * 4);
  float4 s4o = *(const float4*)(S + 1 * 64 + w * 16 + quad * 4);

  for (int kt2 = 0; kt2 < 16; ++kt2) {
    int kne = (2 * kt2 + 2) & 31, kno = (2 * kt2 + 3) & 31;
    int k2n = (kt2 + 1) & 15;
    short8 nkae0 = *(const short8*)(wsb + KA_OFF + frag_idx(bh, kne, w, 0, lane));
    short8 nkae1 = *(const short8*)(wsb + KA_OFF + frag_idx(bh, kne, w, 1, lane));
    short8 nkao0 = *(const short8*)(wsb + KA_OFF + frag_idx(bh, kno, w, 0, lane));
    short8 nkao1 = *(const short8*)(wsb + KA_OFF + frag_idx(bh, kno, w, 1, lane));
    short8 nvb8[4];
#pragma unroll
    for (int et = 0; et < 4; ++et)
      nvb8[et] = *(const short8*)(wsb + VB_OFF + vb8_idx(bh, k2n, w, et, lane));
    float4 ns4e = *(const float4*)(S + kne * 64 + w * 16 + quad * 4);
    float4 ns4o = *(const float4*)(S + kno * 64 + w * 16 + quad * 4);

#pragma unroll
    for (int nt = 0; nt < 4; ++nt) {
      f32x4 ye = (f32x4){0.f, 0.f, 0.f, 0.f};
      f32x4 yo = (f32x4){0.f, 0.f, 0.f, 0.f};
      __builtin_amdgcn_s_setprio(1);
      ye = __builtin_amdgcn_mfma_f32_16x16x32_bf16(kae0, qf[nt][0], ye, 0, 0, 0);
      ye = __builtin_amdgcn_mfma_f32_16x16x32_bf16(kae1, qf[nt][1], ye, 0, 0, 0);
      yo = __builtin_amdgcn_mfma_f32_16x16x32_bf16(kao0, qf[nt][0], yo, 0, 0, 0);
      yo = __builtin_amdgcn_mfma_f32_16x16x32_bf16(kao1, qf[nt][1], yo, 0, 0, 0);
      __builtin_amdgcn_s_setprio(0);
      short8 pa8;
      pa8[0] = (short)f2bf(__builtin_amdgcn_exp2f(ye[0]) * s4e.x);
      pa8[1] = (short)f2bf(__builtin_amdgcn_exp2f(ye[1]) * s4e.y);
      pa8[2] = (short)f2bf(__builtin_amdgcn_exp2f(ye[2]) * s4e.z);
      pa8[3] = (short)f2bf(__builtin_amdgcn_exp2f(ye[3]) * s4e.w);
      pa8[4] = (short)f2bf(__builtin_amdgcn_exp2f(yo[0]) * s4o.x);
      pa8[5] = (short)f2bf(__builtin_amdgcn_exp2f(yo[1]) * s4o.y);
      pa8[6] = (short)f2bf(__builtin_amdgcn_exp2f(yo[2]) * s4o.z);
      pa8[7] = (short)f2bf(__builtin_amdgcn_exp2f(yo[3]) * s4o.w);
      __builtin_amdgcn_s_setprio(1);
#pragma unroll
      for (int et = 0; et < 4; ++et)
        oacc[nt][et] = __builtin_amdgcn_mfma_f32_16x16x32_bf16(pa8, vb8[et], oacc[nt][et], 0, 0, 0);
      __builtin_amdgcn_s_setprio(0);
    }
    kae0 = nkae0; kae1 = nkae1; kao0 = nkao0; kao1 = nkao1;
#pragma unroll
    for (int et = 0; et < 4; ++et) vb8[et] = nvb8[et];
    s4e = ns4e; s4o = ns4o;
  }

  __shared__ float red[4][64][68];
#pragma unroll
  for (int nt = 0; nt < 4; ++nt)
#pragma unroll
    for (int et = 0; et < 4; ++et)
#pragma unroll
      for (int r = 0; r < 4; ++r)
        red[w][nt * 16 + quad * 4 + r][et * 16 + l16] = oacc[nt][et][r];
  __syncthreads();
  float* og = out + ((size_t)b * LL + qbase + w * 16) * 512 + h * 64;
#pragma unroll
  for (int i = 0; i < 16; ++i) {
    float s = red[0][w * 16 + i][lane] + red[1][w * 16 + i][lane] +
              red[2][w * 16 + i][lane] + red[3][w * 16 + i][lane];
    og[(size_t)i * 512 + lane] = s;
  }
}

extern "C" void kernel_launch(void* const* d_in, const int* in_sizes, int n_in,
                              void* d_out, int out_size, void* d_ws, size_t ws_size,
                              hipStream_t stream) {
  const float* keys    = (const float*)d_in[0];
  const float* queries = (const float*)d_in[1];
  const float* values  = (const float*)d_in[2];
  const float* WQ      = (const float*)d_in[3];
  const float* WK      = (const float*)d_in[4];
  const float* WV      = (const float*)d_in[5];
  float* out = (float*)d_out;
  u16* wsb = (u16*)d_ws;

  prep_kernel<<<dim3(1152), 256, 0, stream>>>(queries, keys, values, WQ, WK, WV, wsb);
  proj_kernel<<<dim3(32, 16, 3), 256, 0, stream>>>(wsb);
  stats_kernel<<<dim3(16, 32), 256, 0, stream>>>(wsb);
  attn_kernel<<<dim3(16, 32), 256, 0, stream>>>(wsb, out);
}